// Round 3
// baseline (5424.052 us; speedup 1.0000x reference)
//
#include <hip/hip_runtime.h>

#define B_ 8
#define N_ 32768
#define S_ 1024
#define C_ 96
#define T_ 1024           // threads per FPS block (16 waves, 4/SIMD, 1 block/CU)
#define PK 16             // float2 pairs per thread (32 points)

typedef float f2v __attribute__((ext_vector_type(2)));

// d_out layout (float32, concatenated):
//   [0, B*S*3)                      new_xyz  (B,S,3)
//   [B*S*3, B*S*3+B*C*S)            new_fea  (B,C,S)
//   [B*S*3+B*C*S, +B*S)             indices  (B,S) as float

__global__ __launch_bounds__(T_)
__attribute__((amdgpu_waves_per_eu(4, 4)))   // pin 4 waves/SIMD -> 128-VGPR budget
void fps_kernel(
    const float* __restrict__ xyz,   // (B, N, 3)
    float* __restrict__ out)
{
#pragma clang fp contract(off)
  const int b    = blockIdx.x;
  const int tid  = threadIdx.x;
  const int wv   = tid >> 6;        // wave id 0..15
  const int lane = tid & 63;
  const float* xb = xyz + (size_t)b * N_ * 3;

  float* out_xyz = out;
  float* out_idx = out + (size_t)B_*S_*3 + (size_t)B_*C_*S_;

  // Running min sq-dists, thread-private f2v slots: pair k of thread tid at
  // s_dist2[k*T_ + tid]. ds_read_b64/ds_write_b64, banks perfectly balanced
  // (128 dwords / 32 banks = 4 bank-cycles = data-movement minimum).
  __shared__ f2v   s_dist2[N_/2];   // 128 KiB
  __shared__ float s_v[2][16];      // per-wave partial max, parity double-buffered
  __shared__ int   s_i[2][16];

  // Coordinates in REGISTERS as float2 pairs (global points 2k*T_+tid, (2k+1)*T_+tid).
  f2v X[PK], Y[PK], Z[PK];
  #pragma unroll
  for (int k = 0; k < PK; ++k) {
    const int g0 = (2*k)   * T_ + tid;
    const int g1 = (2*k+1) * T_ + tid;
    X[k] = (f2v){xb[g0*3+0], xb[g1*3+0]};
    Y[k] = (f2v){xb[g0*3+1], xb[g1*3+1]};
    Z[k] = (f2v){xb[g0*3+2], xb[g1*3+2]};
    s_dist2[k*T_ + tid] = (f2v){1e10f, 1e10f};
  }
  // No barrier: every thread touches only its own s_dist2 slots.

  int cur = 0;
  for (int s = 0; s < S_; ++s) {
    // Uniform broadcast load of current point's coords (L1/L2-hit, once/step).
    const float cx = xb[cur*3+0];
    const float cy = xb[cur*3+1];
    const float cz = xb[cur*3+2];
    if (tid == 0) {
      out_idx[(size_t)b*S_ + s] = (float)cur;
      float* o = out_xyz + ((size_t)b*S_ + s)*3;
      o[0] = cx; o[1] = cy; o[2] = cz;
    }
    const f2v c2x = (f2v){cx, cx};
    const f2v c2y = (f2v){cy, cy};
    const f2v c2z = (f2v){cz, cz};

    // Update min-dists (packed fp32, exact IEEE order, no contraction);
    // per-thread argmax with first-index tie-break (ascending k, strict >).
    float bv = -1.0f;
    int   bj = 0;
    #pragma unroll
    for (int k = 0; k < PK; ++k) {
      const int o2 = k * T_ + tid;
      const f2v od = s_dist2[o2];
      const f2v dx = X[k] - c2x;
      const f2v dy = Y[k] - c2y;
      const f2v dz = Z[k] - c2z;
      const f2v d  = (dx*dx + dy*dy) + dz*dz;   // ((dx^2+dy^2)+dz^2), np order
      f2v nd;
      nd.x = fminf(od.x, d.x);
      nd.y = fminf(od.y, d.y);
      // Exec-masked store: only lanes that improved pay LDS bank bandwidth;
      // in steady state almost none do. Stored value is the exact fminf result.
      if (d.x < od.x || d.y < od.y) s_dist2[o2] = nd;
      if (nd.x > bv) { bv = nd.x; bj = 2*k;   }
      if (nd.y > bv) { bv = nd.y; bj = 2*k+1; }
    }
    int bg = (bj << 10) + tid;    // true global point index (T_ == 1024)

    // In-wave argmax reduce (lane 0 ends with wave winner), smallest-index ties.
    #pragma unroll
    for (int off = 32; off > 0; off >>= 1) {
      const float ov = __shfl_down(bv, off);
      const int   og = __shfl_down(bg, off);
      if (ov > bv || (ov == bv && og < bg)) { bv = ov; bg = og; }
    }
    const int par = s & 1;
    if (lane == 0) { s_v[par][wv] = bv; s_i[par][wv] = bg; }
    __syncthreads();   // single barrier per step (parity buffers make it safe)

    // Every wave redundantly reduces the 16 partials -> block winner in all lanes.
    float v = s_v[par][lane & 15];
    int   g = s_i[par][lane & 15];
    #pragma unroll
    for (int m = 8; m > 0; m >>= 1) {
      const float ov = __shfl_xor(v, m);
      const int   og = __shfl_xor(g, m);
      if (ov > v || (ov == v && og < g)) { v = ov; g = og; }
    }
    cur = g;
  }
}

__global__ void gather_fea_kernel(
    const float* __restrict__ feat,   // (B, C, N)
    const float* __restrict__ idxf,   // (B, S) float indices (in d_out)
    float* __restrict__ out_fea)      // (B, C, S)
{
  const int t = blockIdx.x * blockDim.x + threadIdx.x;
  if (t >= B_ * C_ * S_) return;
  const int s  = t & (S_ - 1);
  const int bc = t >> 10;           // S_ == 1024
  const int c  = bc % C_;
  const int b  = bc / C_;
  const int idx = (int)idxf[(size_t)b * S_ + s];
  out_fea[t] = feat[((size_t)b * C_ + c) * (size_t)N_ + idx];
}

extern "C" void kernel_launch(void* const* d_in, const int* in_sizes, int n_in,
                              void* d_out, int out_size, void* d_ws, size_t ws_size,
                              hipStream_t stream) {
  const float* xyz  = (const float*)d_in[0];   // (B,N,3)
  const float* feat = (const float*)d_in[1];   // (B,C,N)
  float* out = (float*)d_out;

  float* out_fea = out + (size_t)B_ * S_ * 3;
  float* out_idx = out + (size_t)B_ * S_ * 3 + (size_t)B_ * C_ * S_;
  (void)d_ws; (void)ws_size; (void)in_sizes; (void)n_in; (void)out_size;

  fps_kernel<<<B_, T_, 0, stream>>>(xyz, out);

  const int total = B_ * C_ * S_;
  gather_fea_kernel<<<(total + 255) / 256, 256, 0, stream>>>(feat, out_idx, out_fea);
}

// Round 4
// 3841.145 us; speedup vs baseline: 1.4121x; 1.4121x over previous
//
#include <hip/hip_runtime.h>

#define B_ 8
#define N_ 32768
#define S_ 1024
#define C_ 96
#define T_ 1024           // threads per FPS block (16 waves, 4/SIMD, 1 block/CU)
#define PK 16             // float2 pairs per thread (32 points)

typedef float f2v __attribute__((ext_vector_type(2)));

// d_out layout (float32, concatenated):
//   [0, B*S*3)                      new_xyz  (B,S,3)
//   [B*S*3, B*S*3+B*C*S)            new_fea  (B,C,S)
//   [B*S*3+B*C*S, +B*S)             indices  (B,S) as float

__global__ __launch_bounds__(T_)
__attribute__((amdgpu_waves_per_eu(4, 4)))   // 4 waves/SIMD -> 128-VGPR budget
void fps_kernel(
    const float* __restrict__ xyz,   // (B, N, 3)
    float* __restrict__ out)
{
#pragma clang fp contract(off)
  const int b    = blockIdx.x;
  const int tid  = threadIdx.x;
  const int wv   = tid >> 6;        // wave id 0..15
  const int lane = tid & 63;
  const float* xb = xyz + (size_t)b * N_ * 3;

  float* out_xyz = out;
  float* out_idx = out + (size_t)B_*S_*3 + (size_t)B_*C_*S_;

  // Running min sq-dists, thread-private f2v slots at s_dist2[k*T_ + tid].
  // ds_read_b64/ds_write_b64, perfectly bank-balanced (4 bank-cycles/instr).
  __shared__ f2v   s_dist2[N_/2];   // 128 KiB
  __shared__ float s_v[2][16];      // per-wave partial max, parity double-buffered
  __shared__ int   s_i[2][16];

  // Coordinates as float2 pairs (global points 2k*T_+tid, (2k+1)*T_+tid).
  f2v X[PK], Y[PK], Z[PK];
  #pragma unroll
  for (int k = 0; k < PK; ++k) {
    const int g0 = (2*k)   * T_ + tid;
    const int g1 = (2*k+1) * T_ + tid;
    X[k] = (f2v){xb[g0*3+0], xb[g1*3+0]};
    Y[k] = (f2v){xb[g0*3+1], xb[g1*3+1]};
    Z[k] = (f2v){xb[g0*3+2], xb[g1*3+2]};
    s_dist2[k*T_ + tid] = (f2v){1e10f, 1e10f};
  }
  // PIN the coords into VGPRs: asm-defined values are not rematerializable,
  // so the allocator cannot "spill" them by re-loading from global each step.
  #pragma unroll
  for (int k = 0; k < PK; ++k) {
    asm volatile("" : "+v"(X[k]), "+v"(Y[k]), "+v"(Z[k]));
  }
  // No barrier: every thread touches only its own s_dist2 slots.

  int cur = 0;
  for (int s = 0; s < S_; ++s) {
    // Uniform broadcast load of current point's coords (one line, L2-hit).
    const float cx = xb[cur*3+0];
    const float cy = xb[cur*3+1];
    const float cz = xb[cur*3+2];
    if (tid == 0) {
      out_idx[(size_t)b*S_ + s] = (float)cur;
      float* o = out_xyz + ((size_t)b*S_ + s)*3;
      o[0] = cx; o[1] = cy; o[2] = cz;
    }
    const f2v c2x = (f2v){cx, cx};
    const f2v c2y = (f2v){cy, cy};
    const f2v c2z = (f2v){cz, cz};

    // Update min-dists (packed fp32, exact IEEE order, no contraction);
    // per-thread argmax with first-index tie-break (ascending k, strict >).
    float bv = -1.0f;
    int   bj = 0;
    #pragma unroll
    for (int k = 0; k < PK; ++k) {
      const int o2 = k * T_ + tid;
      const f2v od = s_dist2[o2];
      const f2v dx = X[k] - c2x;
      const f2v dy = Y[k] - c2y;
      const f2v dz = Z[k] - c2z;
      const f2v d  = (dx*dx + dy*dy) + dz*dz;   // ((dx^2+dy^2)+dz^2), np order
      f2v nd;
      nd.x = fminf(od.x, d.x);
      nd.y = fminf(od.y, d.y);
      s_dist2[o2] = nd;              // unconditional b64 store (round-3 cond regressed)
      if (nd.x > bv) { bv = nd.x; bj = 2*k;   }
      if (nd.y > bv) { bv = nd.y; bj = 2*k+1; }
    }
    int bg = (bj << 10) + tid;    // true global point index (T_ == 1024)

    // In-wave argmax reduce (lane 0 ends with wave winner), smallest-index ties.
    #pragma unroll
    for (int off = 32; off > 0; off >>= 1) {
      const float ov = __shfl_down(bv, off);
      const int   og = __shfl_down(bg, off);
      if (ov > bv || (ov == bv && og < bg)) { bv = ov; bg = og; }
    }
    const int par = s & 1;
    if (lane == 0) { s_v[par][wv] = bv; s_i[par][wv] = bg; }
    __syncthreads();   // single barrier per step (parity buffers make it safe)

    // Every wave redundantly reduces the 16 partials -> block winner in all lanes.
    float v = s_v[par][lane & 15];
    int   g = s_i[par][lane & 15];
    #pragma unroll
    for (int m = 8; m > 0; m >>= 1) {
      const float ov = __shfl_xor(v, m);
      const int   og = __shfl_xor(g, m);
      if (ov > v || (ov == v && og < g)) { v = ov; g = og; }
    }
    cur = g;
  }
}

__global__ void gather_fea_kernel(
    const float* __restrict__ feat,   // (B, C, N)
    const float* __restrict__ idxf,   // (B, S) float indices (in d_out)
    float* __restrict__ out_fea)      // (B, C, S)
{
  const int t = blockIdx.x * blockDim.x + threadIdx.x;
  if (t >= B_ * C_ * S_) return;
  const int s  = t & (S_ - 1);
  const int bc = t >> 10;           // S_ == 1024
  const int c  = bc % C_;
  const int b  = bc / C_;
  const int idx = (int)idxf[(size_t)b * S_ + s];
  out_fea[t] = feat[((size_t)b * C_ + c) * (size_t)N_ + idx];
}

extern "C" void kernel_launch(void* const* d_in, const int* in_sizes, int n_in,
                              void* d_out, int out_size, void* d_ws, size_t ws_size,
                              hipStream_t stream) {
  const float* xyz  = (const float*)d_in[0];   // (B,N,3)
  const float* feat = (const float*)d_in[1];   // (B,C,N)
  float* out = (float*)d_out;

  float* out_fea = out + (size_t)B_ * S_ * 3;
  float* out_idx = out + (size_t)B_ * S_ * 3 + (size_t)B_ * C_ * S_;
  (void)d_ws; (void)ws_size; (void)in_sizes; (void)n_in; (void)out_size;

  fps_kernel<<<B_, T_, 0, stream>>>(xyz, out);

  const int total = B_ * C_ * S_;
  gather_fea_kernel<<<(total + 255) / 256, 256, 0, stream>>>(feat, out_idx, out_fea);
}